// Round 2
// baseline (8240.614 us; speedup 1.0000x reference)
//
#include <hip/hip_runtime.h>

#define NB 256
#define BLK 512
#define Tt 96
#define TS 95
#define DYc 90
#define DPc 80
#define DINc 170
#define Hh 4096

// ws float offsets (total need ~2.1 MB)
#define UPo 0ull                 // 95*4096
#define Yo  389120ull            // 96*96 (row stride 96)
#define P2o 398336ull            // 16*4096
#define P3o 463872ull            // 16*4096
#define BARo 529408ull           // 64 uints
#define WS_NEED_BYTES (529472ull * 4ull)

// output float offsets
#define O_YU 0
#define O_YL 8640
#define O_P1 17280
#define O_PU 24960
#define O_PL 32640

// Grid barrier: count at bar[0], generation at bar[16] (separate 64B lines).
// Agent-scope acq/rel (valid across non-coherent XCD L2s). Timeout escape so a
// failure can never hang the GPU.
__device__ __forceinline__ void gbar(unsigned* bar) {
  __syncthreads();
  if (threadIdx.x == 0) {
    unsigned g = __hip_atomic_load(&bar[16], __ATOMIC_RELAXED, __HIP_MEMORY_SCOPE_AGENT);
    unsigned a = __hip_atomic_fetch_add(&bar[0], 1u, __ATOMIC_ACQ_REL, __HIP_MEMORY_SCOPE_AGENT);
    if (a == (unsigned)(NB - 1)) {
      __hip_atomic_store(&bar[0], 0u, __ATOMIC_RELAXED, __HIP_MEMORY_SCOPE_AGENT);
      __hip_atomic_store(&bar[16], g + 1u, __ATOMIC_RELEASE, __HIP_MEMORY_SCOPE_AGENT);
    } else {
      unsigned spins = 0;
      while (__hip_atomic_load(&bar[16], __ATOMIC_RELAXED, __HIP_MEMORY_SCOPE_AGENT) == g) {
        __builtin_amdgcn_s_sleep(2);
        if (++spins > (1u << 20)) break;  // escape hatch; never hit when healthy
      }
      (void)__hip_atomic_load(&bar[16], __ATOMIC_ACQUIRE, __HIP_MEMORY_SCOPE_AGENT);
    }
  }
  __syncthreads();
}

extern "C" __global__ void initk(unsigned* bar) {
  if (threadIdx.x < 32) bar[threadIdx.x] = 0u;
}

extern "C" __global__ __launch_bounds__(BLK, 1)
void scan_kernel(const float* __restrict__ J,   const float* __restrict__ Pp,
                 const float* __restrict__ UppY, const float* __restrict__ LowY,
                 const float* __restrict__ UppP, const float* __restrict__ LowP,
                 const float* __restrict__ W1,  const float* __restrict__ b1,
                 const float* __restrict__ W2,  const float* __restrict__ b2,
                 const float* __restrict__ W3,  const float* __restrict__ b3,
                 const float* __restrict__ W4,  const float* __restrict__ b4,
                 const float* __restrict__ scY, const float* __restrict__ mnY,
                 const float* __restrict__ scP, const float* __restrict__ mnP,
                 float* __restrict__ out, float* __restrict__ ws) {
  const int bid = blockIdx.x, tid = threadIdx.x;
  const int g  = bid & 15;   // k-group (rows g*256..g*256+255)
  const int cb = bid >> 4;   // column chunk (cols cb*256..cb*256+255)
  float* UP = ws + UPo;
  float* Y  = ws + Yo;
  float* P2 = ws + P2o;
  float* P3 = ws + P3o;
  unsigned* bar = (unsigned*)(ws + BARo);

  __shared__ float ys[96];
  __shared__ float hs[256];
  __shared__ float red[8][260];
  __shared__ float h3L[16];

  // ---------------- pre-phase ----------------
  // UP[t][j] = b1[j] + u_t . W1[90:170][j]  (natural layout, coalesced over j)
  for (int task = bid; task < TS * 8; task += NB) {
    const int t = task >> 3, jc = task & 7;
    const int j = jc * 512 + tid;
    const float* Jr = J + (size_t)t * DINc + DYc;
    float acc = b1[j];
#pragma unroll 8
    for (int k = 0; k < DPc; ++k) acc = fmaf(Jr[k], W1[(size_t)(DYc + k) * Hh + j], acc);
    UP[(size_t)t * Hh + j] = acc;
  }
  // y rows: row0 = y0; rows 1..95 = b4 (atomicAdd accumulates W4 partials)
  if (bid == 0 && tid < DYc) Y[tid] = J[tid];
  if (bid >= 1 && bid <= TS && tid < DYc) Y[bid * 96 + tid] = b4[tid];
  // Obj_P (independent of scan)
  if (bid < Tt && tid < DPc) {
    const int t = bid, k = tid;
    const float ph = fmaf(J[(size_t)t * DINc + DYc + k], scP[k], mnP[k]);
    out[O_P1 + t * DPc + k] = ph * Pp[t * DPc + k];
    out[O_PU + t * DPc + k] = fmaxf(ph - UppP[t * DPc + k], 0.f);
    out[O_PL + t * DPc + k] = fmaxf(LowP[t * DPc + k] - ph, 0.f);
  }
  gbar(bar);

  // ---------------- scan: 95 steps, 3 grid barriers each ----------------
  const int w = tid >> 6, l = tid & 63;
  const size_t colbase = (size_t)cb * 256 + (size_t)l * 4;

  for (int t = 0; t < TS; ++t) {
    // Ph1: hs = relu(h1[g-slice]) computed in-block; then h2 partial over W2
    if (tid < DYc) ys[tid] = Y[t * 96 + tid];
    __syncthreads();
    if (tid < 256) {
      const int k = g * 256 + tid;
      float acc = UP[(size_t)t * Hh + k];
#pragma unroll 6
      for (int q = 0; q < DYc; ++q) acc = fmaf(ys[q], W1[(size_t)q * Hh + k], acc);
      hs[tid] = fmaxf(acc, 0.f);
    }
    __syncthreads();
    {
      float4 acc = make_float4(0.f, 0.f, 0.f, 0.f);
      const int kb = w * 32;
      const float* Wp = W2 + (size_t)(g * 256 + kb) * Hh + colbase;
#pragma unroll 8
      for (int kk = 0; kk < 32; ++kk) {
        const float hv = hs[kb + kk];
        const float4 wv = *(const float4*)(Wp + (size_t)kk * Hh);
        acc.x = fmaf(hv, wv.x, acc.x);
        acc.y = fmaf(hv, wv.y, acc.y);
        acc.z = fmaf(hv, wv.z, acc.z);
        acc.w = fmaf(hv, wv.w, acc.w);
      }
      *(float4*)&red[w][l * 4] = acc;
    }
    __syncthreads();
    if (tid < 256) {
      float s = red[0][tid];
#pragma unroll
      for (int w2 = 1; w2 < 8; ++w2) s += red[w2][tid];
      P2[(size_t)g * Hh + cb * 256 + tid] = s;
    }
    gbar(bar);

    // Ph2: hs = relu(b2 + sum_g' P2[g'][g-slice]); then h3 partial over W3
    if (tid < 256) {
      const int k = g * 256 + tid;
      float v = b2[k];
#pragma unroll
      for (int gp = 0; gp < 16; ++gp) v += P2[(size_t)gp * Hh + k];
      hs[tid] = fmaxf(v, 0.f);
    }
    __syncthreads();
    {
      float4 acc = make_float4(0.f, 0.f, 0.f, 0.f);
      const int kb = w * 32;
      const float* Wp = W3 + (size_t)(g * 256 + kb) * Hh + colbase;
#pragma unroll 8
      for (int kk = 0; kk < 32; ++kk) {
        const float hv = hs[kb + kk];
        const float4 wv = *(const float4*)(Wp + (size_t)kk * Hh);
        acc.x = fmaf(hv, wv.x, acc.x);
        acc.y = fmaf(hv, wv.y, acc.y);
        acc.z = fmaf(hv, wv.z, acc.z);
        acc.w = fmaf(hv, wv.w, acc.w);
      }
      *(float4*)&red[w][l * 4] = acc;
    }
    __syncthreads();
    if (tid < 256) {
      float s = red[0][tid];
#pragma unroll
      for (int w2 = 1; w2 < 8; ++w2) s += red[w2][tid];
      P3[(size_t)g * Hh + cb * 256 + tid] = s;
    }
    gbar(bar);

    // Ph3: finalize 16 h3 per block, W4 partial -> atomicAdd into y_{t+1}
    {
      const int j0 = bid * 16;
      if (tid < 16) {
        float v = b3[j0 + tid];
#pragma unroll
        for (int gp = 0; gp < 16; ++gp) v += P3[(size_t)gp * Hh + j0 + tid];
        h3L[tid] = fmaxf(v, 0.f);
      }
      __syncthreads();
      if (tid < DYc) {
        float acc = 0.f;
#pragma unroll
        for (int jj = 0; jj < 16; ++jj)
          acc = fmaf(h3L[jj], W4[(size_t)(j0 + jj) * DYc + tid], acc);
        atomicAdd(&Y[(t + 1) * 96 + tid], acc);
      }
    }
    gbar(bar);
  }

  // ---------------- epilogue: Obj_Y ----------------
  if (bid < Tt && tid < DYc) {
    const float yh = fmaf(Y[bid * 96 + tid], scY[tid], mnY[tid]);
    out[O_YU + bid * DYc + tid] = fmaxf(yh - UppY[bid * DYc + tid], 0.f);
    out[O_YL + bid * DYc + tid] = fmaxf(LowY[bid * DYc + tid] - yh, 0.f);
  }
}

extern "C" void kernel_launch(void* const* d_in, const int* in_sizes, int n_in,
                              void* d_out, int out_size, void* d_ws, size_t ws_size,
                              hipStream_t stream) {
  if (ws_size < WS_NEED_BYTES) return;  // fail loudly (validation) instead of corrupting
  float* ws = (float*)d_ws;
  unsigned* bar = (unsigned*)(ws + BARo);
  initk<<<dim3(1), dim3(64), 0, stream>>>(bar);
  scan_kernel<<<dim3(NB), dim3(BLK), 0, stream>>>(
      (const float*)d_in[0],  (const float*)d_in[1],  (const float*)d_in[2],
      (const float*)d_in[3],  (const float*)d_in[4],  (const float*)d_in[5],
      (const float*)d_in[6],  (const float*)d_in[7],  (const float*)d_in[8],
      (const float*)d_in[9],  (const float*)d_in[10], (const float*)d_in[11],
      (const float*)d_in[12], (const float*)d_in[13], (const float*)d_in[14],
      (const float*)d_in[15], (const float*)d_in[16], (const float*)d_in[17],
      (float*)d_out, ws);
}

// Round 4
// 6808.524 us; speedup vs baseline: 1.2103x; 1.2103x over previous
//
#include <hip/hip_runtime.h>

#define NB 256
#define BLK 512
#define TSn 95
#define DYn 90
#define DPn 80
#define DINn 170
#define Hn 4096

// ---- byte offsets in ws ----
// bf16 path:
#define O_W2B 0ull
#define O_W3B 33554432ull
#define O_W1B 67108864ull
#define O_TAIL_BF16 68501504ull
// tail region (both paths): UP, P2, P3, P4, Y, bar
#define T_UP 0ull
#define T_P2 1556480ull
#define T_P3 1818624ull
#define T_P4 2080768ull
#define T_Y  2179072ull
#define T_BAR 2215936ull
#define T_END 2220288ull
#define NEED_BF16 (O_TAIL_BF16 + T_END)
#define NEED_F32  (T_END)

// out float offsets
#define O_YU 0
#define O_YL 8640
#define O_P1 17280
#define O_PU 24960
#define O_PL 32640

typedef unsigned int uint32;
typedef unsigned short ushort16;

__device__ __forceinline__ float ld_cg(const float* p) {
  return __hip_atomic_load(p, __ATOMIC_RELAXED, __HIP_MEMORY_SCOPE_AGENT);
}
__device__ __forceinline__ void st_cg(float* p, float v) {
  __hip_atomic_store(p, v, __ATOMIC_RELAXED, __HIP_MEMORY_SCOPE_AGENT);
}
__device__ __forceinline__ unsigned f2bf(float f) {
  uint32 u = __float_as_uint(f);
  return (u + 0x7fffu + ((u >> 16) & 1u)) >> 16;  // RNE
}
__device__ __forceinline__ float bflo(uint32 u) { return __uint_as_float(u << 16); }
__device__ __forceinline__ float bfhi(uint32 u) { return __uint_as_float(u & 0xffff0000u); }

// Distributed, invalidation-free grid barrier.
// bar[0..1023]: 64 cumulative counters at stride 16 (64B apart). bar[1024]: generation.
__device__ void gbar(unsigned* bar, unsigned epoch, int bid, int tid) {
  __syncthreads();  // all waves' prior (sc-flagged) stores retired before arrival
  if (bid == 0) {
    if (tid < 64) {
      if (tid == 0)
        __hip_atomic_fetch_add(&bar[0], 1u, __ATOMIC_RELAXED, __HIP_MEMORY_SCOPE_AGENT);
      unsigned spins = 0;
      for (;;) {
        unsigned v = __hip_atomic_load(&bar[tid * 16], __ATOMIC_RELAXED, __HIP_MEMORY_SCOPE_AGENT);
#pragma unroll
        for (int o = 32; o > 0; o >>= 1) v += __shfl_xor(v, o, 64);
        if (v >= epoch * (unsigned)NB) break;
        __builtin_amdgcn_s_sleep(1);
        if (++spins > (1u << 22)) break;
      }
      if (tid == 0)
        __hip_atomic_store(&bar[1024], epoch, __ATOMIC_RELAXED, __HIP_MEMORY_SCOPE_AGENT);
    }
  } else {
    if (tid == 0) {
      __hip_atomic_fetch_add(&bar[(bid & 63) * 16], 1u, __ATOMIC_RELAXED, __HIP_MEMORY_SCOPE_AGENT);
      unsigned spins = 0;
      while (__hip_atomic_load(&bar[1024], __ATOMIC_RELAXED, __HIP_MEMORY_SCOPE_AGENT) < epoch) {
        __builtin_amdgcn_s_sleep(1);
        if (++spins > (1u << 22)) break;
      }
    }
  }
  __syncthreads();
}

// ---------------- prologue kernels ----------------
extern "C" __global__ void zero_bar(unsigned* bar) {
  int i = blockIdx.x * 256 + threadIdx.x;
  if (i < 1088) bar[i] = 0u;
}

#define NP2 8388608ull
#define NP3 16777216ull
#define NPTOT 17125376ull
extern "C" __global__ void conv_kernel(const float2* __restrict__ W2, const float2* __restrict__ W3,
                                       const float2* __restrict__ W1, uint32* __restrict__ o2,
                                       uint32* __restrict__ o3, uint32* __restrict__ o1) {
  size_t stride = (size_t)gridDim.x * blockDim.x;
  for (size_t i = (size_t)blockIdx.x * blockDim.x + threadIdx.x; i < NPTOT; i += stride) {
    float2 f;
    if (i < NP2) f = W2[i];
    else if (i < NP3) f = W3[i - NP2];
    else f = W1[i - NP3];
    uint32 v = f2bf(f.x) | (f2bf(f.y) << 16);
    if (i < NP2) o2[i] = v;
    else if (i < NP3) o3[i - NP2] = v;
    else o1[i - NP3] = v;
  }
}

extern "C" __global__ __launch_bounds__(BLK)
void up_kernel(const float* __restrict__ J, const float* __restrict__ W1,
               const float* __restrict__ b1, float* __restrict__ UP) {
  const int t = blockIdx.x >> 3, jc = blockIdx.x & 7;
  const int j = jc * BLK + threadIdx.x;
  __shared__ float us[DPn];
  if (threadIdx.x < DPn) us[threadIdx.x] = J[(size_t)t * DINn + DYn + threadIdx.x];
  __syncthreads();
  float acc = b1[j];
#pragma unroll 8
  for (int k = 0; k < DPn; ++k) acc = fmaf(us[k], W1[(size_t)(DYn + k) * Hn + j], acc);
  UP[(size_t)t * Hn + j] = acc;
}

// ---------------- scan ----------------
template <bool BF16>
__device__ __forceinline__ void stream_mm(const void* __restrict__ Wp_, const float* __restrict__ hs,
                                          float (&red)[8][264], int K0, int C0, int w, int l,
                                          float* __restrict__ Pout, int tid) {
  const int lh = l & 31, kp = l >> 5;
  float a[8] = {0.f, 0.f, 0.f, 0.f, 0.f, 0.f, 0.f, 0.f};
  if (BF16) {
    const ushort16* W = (const ushort16*)Wp_;
    const uint4* wp = (const uint4*)(W + (size_t)(K0 + w * 32 + kp) * Hn + C0 + lh * 8);
#pragma unroll
    for (int i = 0; i < 16; ++i) {
      uint4 u = wp[(size_t)i * 1024];  // advance 2 rows (2*4096 ushort = 1024 uint4)
      float hv = hs[w * 32 + kp + 2 * i];
      a[0] = fmaf(hv, bflo(u.x), a[0]); a[1] = fmaf(hv, bfhi(u.x), a[1]);
      a[2] = fmaf(hv, bflo(u.y), a[2]); a[3] = fmaf(hv, bfhi(u.y), a[3]);
      a[4] = fmaf(hv, bflo(u.z), a[4]); a[5] = fmaf(hv, bfhi(u.z), a[5]);
      a[6] = fmaf(hv, bflo(u.w), a[6]); a[7] = fmaf(hv, bfhi(u.w), a[7]);
    }
  } else {
    const float* W = (const float*)Wp_;
    const float* wp = W + (size_t)(K0 + w * 32 + kp) * Hn + C0 + lh * 8;
#pragma unroll
    for (int i = 0; i < 16; ++i) {
      float4 u0 = *(const float4*)(wp + (size_t)(2 * i) * Hn);
      float4 u1 = *(const float4*)(wp + (size_t)(2 * i) * Hn + 4);
      float hv = hs[w * 32 + kp + 2 * i];
      a[0] = fmaf(hv, u0.x, a[0]); a[1] = fmaf(hv, u0.y, a[1]);
      a[2] = fmaf(hv, u0.z, a[2]); a[3] = fmaf(hv, u0.w, a[3]);
      a[4] = fmaf(hv, u1.x, a[4]); a[5] = fmaf(hv, u1.y, a[5]);
      a[6] = fmaf(hv, u1.z, a[6]); a[7] = fmaf(hv, u1.w, a[7]);
    }
  }
#pragma unroll
  for (int j = 0; j < 8; ++j) a[j] += __shfl_xor(a[j], 32, 64);
  if (kp == 0) {
#pragma unroll
    for (int j = 0; j < 8; ++j) red[w][lh * 8 + j] = a[j];
  }
  __syncthreads();
  if (tid < 256) {
    float s = red[0][tid] + red[1][tid] + red[2][tid] + red[3][tid] +
              red[4][tid] + red[5][tid] + red[6][tid] + red[7][tid];
    st_cg(&Pout[tid], s);
  }
}

template <bool BF16>
__global__ __launch_bounds__(BLK, 1)
void scan_kernel(const float* __restrict__ J, const float* __restrict__ b2,
                 const float* __restrict__ b3, const float* __restrict__ b4,
                 const float* __restrict__ W4, const void* __restrict__ W1p,
                 const void* __restrict__ W2p, const void* __restrict__ W3p,
                 const float* __restrict__ UP, float* __restrict__ P2,
                 float* __restrict__ P3, float* __restrict__ P4,
                 float* __restrict__ Y, unsigned* __restrict__ bar) {
  const int bid = blockIdx.x, tid = threadIdx.x;
  const int g = bid & 15, cb = bid >> 4;
  const int K0 = g * 256, C0 = cb * 256;
  const int w = tid >> 6, l = tid & 63;

  __shared__ float ys[96];
  __shared__ float ysp[4][96];
  __shared__ float hs[256];
  __shared__ float red[8][264];
  __shared__ float h3L[16];

  unsigned ep = 0;

  for (int t = 0; t <= TSn; ++t) {
    // ---- y_t ----
    if (t == 0) {
      if (tid < DYn) ys[tid] = J[tid];
    } else {
      const int p = tid >> 7, d = tid & 127;
      if (d < DYn) {
        const float* pr = P4 + (size_t)(p * 64) * 96 + d;
        float a = 0.f;
#pragma unroll 8
        for (int r = 0; r < 64; ++r) a += ld_cg(pr + r * 96);
        ysp[p][d] = a;
      }
      __syncthreads();
      if (tid < DYn) ys[tid] = b4[tid] + ysp[0][tid] + ysp[1][tid] + ysp[2][tid] + ysp[3][tid];
    }
    __syncthreads();
    if (bid == 0 && tid < DYn) st_cg(&Y[(size_t)t * 96 + tid], ys[tid]);
    if (t == TSn) break;

    // ---- h1 slice (this block's 256 k's) ----
    if (tid < 256) {
      float acc = UP[(size_t)t * Hn + K0 + tid];
      if (BF16) {
        const ushort16* wc = (const ushort16*)W1p + K0 + tid;
#pragma unroll 6
        for (int q = 0; q < DYn; ++q)
          acc = fmaf(ys[q], bflo((uint32)wc[(size_t)q * Hn]), acc);
      } else {
        const float* wc = (const float*)W1p + K0 + tid;
#pragma unroll 6
        for (int q = 0; q < DYn; ++q) acc = fmaf(ys[q], wc[(size_t)q * Hn], acc);
      }
      hs[tid] = fmaxf(acc, 0.f);
    }
    __syncthreads();

    // ---- W2 stream -> P2 partials ----
    stream_mm<BF16>(W2p, hs, red, K0, C0, w, l, P2 + (size_t)g * Hn + C0, tid);
    gbar(bar, ++ep, bid, tid);

    // ---- h2 slice = b2 + sum_g P2 ----
    if (tid < 256) {
      float v = b2[K0 + tid];
#pragma unroll
      for (int gp = 0; gp < 16; ++gp) v += ld_cg(&P2[(size_t)gp * Hn + K0 + tid]);
      hs[tid] = fmaxf(v, 0.f);
    }
    __syncthreads();

    // ---- W3 stream -> P3 partials ----
    stream_mm<BF16>(W3p, hs, red, K0, C0, w, l, P3 + (size_t)g * Hn + C0, tid);
    gbar(bar, ++ep, bid, tid);

    // ---- h3 (16 j's) + W4 partial -> P4[bid] ----
    {
      const int j0 = bid * 16;
      if (tid < 16) {
        float v = b3[j0 + tid];
#pragma unroll
        for (int gp = 0; gp < 16; ++gp) v += ld_cg(&P3[(size_t)gp * Hn + j0 + tid]);
        h3L[tid] = fmaxf(v, 0.f);
      }
      __syncthreads();
      if (tid < DYn) {
        float acc = 0.f;
#pragma unroll
        for (int jj = 0; jj < 16; ++jj)
          acc = fmaf(h3L[jj], W4[(size_t)(j0 + jj) * DYn + tid], acc);
        st_cg(&P4[(size_t)bid * 96 + tid], acc);
      }
    }
    gbar(bar, ++ep, bid, tid);
  }
}

// ---------------- epilogue ----------------
extern "C" __global__ void post_kernel(const float* __restrict__ J, const float* __restrict__ Pp,
                                       const float* __restrict__ UppY, const float* __restrict__ LowY,
                                       const float* __restrict__ UppP, const float* __restrict__ LowP,
                                       const float* __restrict__ scY, const float* __restrict__ mnY,
                                       const float* __restrict__ scP, const float* __restrict__ mnP,
                                       const float* __restrict__ Y, float* __restrict__ out) {
  const int t = blockIdx.x, k = threadIdx.x;
  if (k < DPn) {
    const float ph = fmaf(J[(size_t)t * DINn + DYn + k], scP[k], mnP[k]);
    out[O_P1 + t * DPn + k] = ph * Pp[t * DPn + k];
    out[O_PU + t * DPn + k] = fmaxf(ph - UppP[t * DPn + k], 0.f);
    out[O_PL + t * DPn + k] = fmaxf(LowP[t * DPn + k] - ph, 0.f);
  }
  if (k < DYn) {
    const float yh = fmaf(Y[(size_t)t * 96 + k], scY[k], mnY[k]);
    out[O_YU + t * DYn + k] = fmaxf(yh - UppY[t * DYn + k], 0.f);
    out[O_YL + t * DYn + k] = fmaxf(LowY[t * DYn + k] - yh, 0.f);
  }
}

extern "C" void kernel_launch(void* const* d_in, const int* in_sizes, int n_in,
                              void* d_out, int out_size, void* d_ws, size_t ws_size,
                              hipStream_t stream) {
  const float* J    = (const float*)d_in[0];
  const float* Pp   = (const float*)d_in[1];
  const float* UppY = (const float*)d_in[2];
  const float* LowY = (const float*)d_in[3];
  const float* UppP = (const float*)d_in[4];
  const float* LowP = (const float*)d_in[5];
  const float* W1   = (const float*)d_in[6];
  const float* b1   = (const float*)d_in[7];
  const float* W2   = (const float*)d_in[8];
  const float* b2   = (const float*)d_in[9];
  const float* W3   = (const float*)d_in[10];
  const float* b3   = (const float*)d_in[11];
  const float* W4   = (const float*)d_in[12];
  const float* b4   = (const float*)d_in[13];
  const float* scY  = (const float*)d_in[14];
  const float* mnY  = (const float*)d_in[15];
  const float* scP  = (const float*)d_in[16];
  const float* mnP  = (const float*)d_in[17];
  float* out = (float*)d_out;

  const bool bf16 = ws_size >= NEED_BF16;
  if (!bf16 && ws_size < NEED_F32) return;

  char* base = (char*)d_ws;
  char* tail = base + (bf16 ? O_TAIL_BF16 : 0ull);
  float* UP = (float*)(tail + T_UP);
  float* P2 = (float*)(tail + T_P2);
  float* P3 = (float*)(tail + T_P3);
  float* P4 = (float*)(tail + T_P4);
  float* Y  = (float*)(tail + T_Y);
  unsigned* bar = (unsigned*)(tail + T_BAR);

  zero_bar<<<dim3(5), dim3(256), 0, stream>>>(bar);
  up_kernel<<<dim3(TSn * 8), dim3(BLK), 0, stream>>>(J, W1, b1, UP);

  if (bf16) {
    uint32* w2b = (uint32*)(base + O_W2B);
    uint32* w3b = (uint32*)(base + O_W3B);
    uint32* w1b = (uint32*)(base + O_W1B);
    conv_kernel<<<dim3(4096), dim3(256), 0, stream>>>(
        (const float2*)W2, (const float2*)W3, (const float2*)W1, w2b, w3b, w1b);
    scan_kernel<true><<<dim3(NB), dim3(BLK), 0, stream>>>(
        J, b2, b3, b4, W4, (const void*)w1b, (const void*)w2b, (const void*)w3b,
        UP, P2, P3, P4, Y, bar);
  } else {
    scan_kernel<false><<<dim3(NB), dim3(BLK), 0, stream>>>(
        J, b2, b3, b4, W4, (const void*)W1, (const void*)W2, (const void*)W3,
        UP, P2, P3, P4, Y, bar);
  }
  post_kernel<<<dim3(96, 1, 1), dim3(128), 0, stream>>>(
      J, Pp, UppY, LowY, UppP, LowP, scY, mnY, scP, mnP, Y, out);
}

// Round 5
// 4305.748 us; speedup vs baseline: 1.9139x; 1.5813x over previous
//
#include <hip/hip_runtime.h>

#define NB 256
#define BLK 1024
#define TSn 95
#define DYn 90
#define DPn 80
#define DINn 170
#define Hn 4096

typedef unsigned int uint32;

// ---- ws byte offsets ----
#define O_W2T 0ull
#define O_W3T 33554432ull
#define O_W1T 67108864ull      // 4096 x 96 bf16
#define O_UP  67895296ull      // 95 x 4096 f32
#define O_H1X 69451776ull      // 4096 f32
#define O_H2X 69468160ull      // 4096 f32
#define O_P4  69484544ull      // 256 x 128 f32
#define O_Y   69615616ull      // 96 x 96 f32
#define O_BAR 69652480ull      // 1088 u32
#define WS_NEED 69656832ull

// out float offsets
#define O_YU 0
#define O_YL 8640
#define O_P1 17280
#define O_PU 24960
#define O_PL 32640

__device__ __forceinline__ float ld_cg(const float* p) {
  return __hip_atomic_load(p, __ATOMIC_RELAXED, __HIP_MEMORY_SCOPE_AGENT);
}
__device__ __forceinline__ void st_cg(float* p, float v) {
  __hip_atomic_store(p, v, __ATOMIC_RELAXED, __HIP_MEMORY_SCOPE_AGENT);
}
__device__ __forceinline__ unsigned f2bf(float f) {
  uint32 u = __float_as_uint(f);
  return (u + 0x7fffu + ((u >> 16) & 1u)) >> 16;  // RNE
}
__device__ __forceinline__ float bflo(uint32 u) { return __uint_as_float(u << 16); }
__device__ __forceinline__ float bfhi(uint32 u) { return __uint_as_float(u & 0xffff0000u); }

// Invalidation-free grid barrier (proven in R4). Arrival on 64 distributed
// lines, detection by block 0, generation broadcast. Relaxed agent-scope only
// (no acquire/release -> no L2 invalidation; __syncthreads' vmcnt(0) drain
// orders prior st_cg stores before the arrival RMW).
__device__ void gbar(unsigned* bar, unsigned epoch, int bid, int tid) {
  __syncthreads();
  if (bid == 0) {
    if (tid < 64) {
      if (tid == 0)
        __hip_atomic_fetch_add(&bar[0], 1u, __ATOMIC_RELAXED, __HIP_MEMORY_SCOPE_AGENT);
      unsigned spins = 0;
      for (;;) {
        unsigned v = __hip_atomic_load(&bar[tid * 16], __ATOMIC_RELAXED, __HIP_MEMORY_SCOPE_AGENT);
#pragma unroll
        for (int o = 32; o > 0; o >>= 1) v += __shfl_xor(v, o, 64);
        if (v >= epoch * (unsigned)NB) break;
        __builtin_amdgcn_s_sleep(1);
        if (++spins > (1u << 22)) break;
      }
      if (tid == 0)
        __hip_atomic_store(&bar[1024], epoch, __ATOMIC_RELAXED, __HIP_MEMORY_SCOPE_AGENT);
    }
  } else {
    if (tid == 0) {
      __hip_atomic_fetch_add(&bar[(bid & 63) * 16], 1u, __ATOMIC_RELAXED, __HIP_MEMORY_SCOPE_AGENT);
      unsigned spins = 0;
      while (__hip_atomic_load(&bar[1024], __ATOMIC_RELAXED, __HIP_MEMORY_SCOPE_AGENT) < epoch) {
        __builtin_amdgcn_s_sleep(1);
        if (++spins > (1u << 22)) break;
      }
    }
  }
  __syncthreads();
}

// ---------------- prologue kernels ----------------
extern "C" __global__ void zero_bar(unsigned* bar) {
  int i = blockIdx.x * 256 + threadIdx.x;
  if (i < 1088) bar[i] = 0u;
}

// Transpose 4096x4096 f32 -> bf16, 64x64 LDS tiles. grid 8192 (2 matrices).
extern "C" __global__ __launch_bounds__(256)
void t44_kernel(const float* __restrict__ W2, const float* __restrict__ W3,
                uint32* __restrict__ W2T, uint32* __restrict__ W3T) {
  const int mat = blockIdx.x >> 12;
  const int m = blockIdx.x & 4095;
  const float* src = mat ? W3 : W2;
  uint32* dst = mat ? W3T : W2T;
  const int j0 = (m >> 6) * 64, k0 = (m & 63) * 64;
  const int t = threadIdx.x;
  __shared__ float lds[64][65];
  const int jl = t & 63, kb = t >> 6;
#pragma unroll
  for (int i = 0; i < 16; ++i) {
    const int kl = kb + 4 * i;
    lds[kl][jl] = src[(size_t)(k0 + kl) * Hn + j0 + jl];
  }
  __syncthreads();
  const int kp = t & 31, jb = t >> 5;
#pragma unroll
  for (int i = 0; i < 8; ++i) {
    const int jr = jb + 8 * i;
    uint32 v = f2bf(lds[2 * kp][jr]) | (f2bf(lds[2 * kp + 1][jr]) << 16);
    dst[(size_t)(j0 + jr) * 2048 + (k0 >> 1) + kp] = v;
  }
}

// W1 (rows q<90, the y-part) -> W1T[j][q] bf16, stride 96 (zero-pad q>=90).
extern "C" __global__ __launch_bounds__(256)
void t1_kernel(const float* __restrict__ W1, unsigned short* __restrict__ W1T) {
  const int j0 = blockIdx.x * 64;
  const int t = threadIdx.x;
  const int jl = t & 63, q0 = t >> 6;
  for (int q = q0; q < 96; q += 4) {
    float v = (q < DYn) ? W1[(size_t)q * Hn + j0 + jl] : 0.f;
    W1T[(size_t)(j0 + jl) * 96 + q] = (unsigned short)f2bf(v);
  }
}

extern "C" __global__ __launch_bounds__(512)
void up_kernel(const float* __restrict__ J, const float* __restrict__ W1,
               const float* __restrict__ b1, float* __restrict__ UP) {
  const int t = blockIdx.x >> 3, jc = blockIdx.x & 7;
  const int j = jc * 512 + threadIdx.x;
  __shared__ float us[DPn];
  if (threadIdx.x < DPn) us[threadIdx.x] = J[(size_t)t * DINn + DYn + threadIdx.x];
  __syncthreads();
  float acc = b1[j];
#pragma unroll 8
  for (int k = 0; k < DPn; ++k) acc = fmaf(us[k], W1[(size_t)(DYn + k) * Hn + j], acc);
  UP[(size_t)t * Hn + j] = acc;
}

// ---------------- scan ----------------
// One wave streams one transposed-weight row (8 KB bf16) against hv[] in LDS.
__device__ __forceinline__ float row_dot(const uint32* __restrict__ WT, int j,
                                         const float* __restrict__ hv, int l) {
  const uint4* wrow = (const uint4*)WT + (size_t)j * 512;
  float a = 0.f;
#pragma unroll
  for (int i = 0; i < 8; ++i) {
    uint4 u = wrow[i * 64 + l];
    const int k0 = i * 512 + l * 8;
    float4 ha = *(const float4*)&hv[k0];
    float4 hb = *(const float4*)&hv[k0 + 4];
    a = fmaf(ha.x, bflo(u.x), a); a = fmaf(ha.y, bfhi(u.x), a);
    a = fmaf(ha.z, bflo(u.y), a); a = fmaf(ha.w, bfhi(u.y), a);
    a = fmaf(hb.x, bflo(u.z), a); a = fmaf(hb.y, bfhi(u.z), a);
    a = fmaf(hb.z, bflo(u.w), a); a = fmaf(hb.w, bfhi(u.w), a);
  }
#pragma unroll
  for (int o = 32; o > 0; o >>= 1) a += __shfl_xor(a, o, 64);
  return a;
}

extern "C" __global__ __launch_bounds__(BLK, 1)
void scan2_kernel(const float* __restrict__ J, const float* __restrict__ b2,
                  const float* __restrict__ b3, const float* __restrict__ b4,
                  const float* __restrict__ W4, const unsigned short* __restrict__ W1T,
                  const uint32* __restrict__ W2T, const uint32* __restrict__ W3T,
                  const float* __restrict__ UP, float* __restrict__ h1x,
                  float* __restrict__ h2x, float* __restrict__ P4,
                  float* __restrict__ Y, unsigned* __restrict__ bar) {
  const int bid = blockIdx.x, tid = threadIdx.x;
  const int w = tid >> 6, l = tid & 63;
  const int j0 = bid * 16;

  __shared__ float hv[4096];
  __shared__ float ysp[8][128];
  __shared__ float ys[96];
  __shared__ float h3L[16];

  unsigned ep = 0;

  for (int t = 0; t <= TSn; ++t) {
    // ---- phase A: y_t ----
    if (t == 0) {
      if (tid < DYn) ys[tid] = J[tid];
      __syncthreads();
    } else {
      const int d = tid & 127, r0 = tid >> 7;
      float a = 0.f;
      if (d < DYn) {
        const float* pr = P4 + (size_t)r0 * 128 + d;
#pragma unroll 8
        for (int r = 0; r < 32; ++r) a += ld_cg(pr + (size_t)r * 8 * 128);
      }
      ysp[r0][d] = a;
      __syncthreads();
      if (tid < DYn)
        ys[tid] = b4[tid] + ysp[0][tid] + ysp[1][tid] + ysp[2][tid] + ysp[3][tid] +
                  ysp[4][tid] + ysp[5][tid] + ysp[6][tid] + ysp[7][tid];
      __syncthreads();
    }
    if (bid == 0 && tid < DYn) Y[(size_t)t * 96 + tid] = ys[tid];
    if (t == TSn) break;

    // h1 slice: 16 columns, trivial 90-term dots
    if (tid < 16) {
      const int j = j0 + tid;
      const unsigned short* wr = W1T + (size_t)j * 96;
      float acc = UP[(size_t)t * Hn + j];
#pragma unroll 6
      for (int q = 0; q < DYn; ++q) acc = fmaf(ys[q], bflo((uint32)wr[q]), acc);
      st_cg(&h1x[j], fmaxf(acc, 0.f));
    }
    gbar(bar, ++ep, bid, tid);

    // ---- phase B: h2 slice from full h1 ----
#pragma unroll
    for (int i = 0; i < 4; ++i) hv[tid + 1024 * i] = ld_cg(&h1x[tid + 1024 * i]);
    __syncthreads();
    {
      float a = row_dot(W2T, j0 + w, hv, l);
      if (l == 0) st_cg(&h2x[j0 + w], fmaxf(b2[j0 + w] + a, 0.f));
    }
    gbar(bar, ++ep, bid, tid);

    // ---- phase C: h3 slice (local only) + W4 partial ----
#pragma unroll
    for (int i = 0; i < 4; ++i) hv[tid + 1024 * i] = ld_cg(&h2x[tid + 1024 * i]);
    __syncthreads();
    {
      float a = row_dot(W3T, j0 + w, hv, l);
      if (l == 0) h3L[w] = fmaxf(b3[j0 + w] + a, 0.f);
    }
    __syncthreads();
    if (tid < DYn) {
      float acc = 0.f;
#pragma unroll
      for (int jj = 0; jj < 16; ++jj)
        acc = fmaf(h3L[jj], W4[(size_t)(j0 + jj) * DYn + tid], acc);
      st_cg(&P4[(size_t)bid * 128 + tid], acc);
    }
    gbar(bar, ++ep, bid, tid);
  }
}

// ---------------- epilogue ----------------
extern "C" __global__ void post_kernel(const float* __restrict__ J, const float* __restrict__ Pp,
                                       const float* __restrict__ UppY, const float* __restrict__ LowY,
                                       const float* __restrict__ UppP, const float* __restrict__ LowP,
                                       const float* __restrict__ scY, const float* __restrict__ mnY,
                                       const float* __restrict__ scP, const float* __restrict__ mnP,
                                       const float* __restrict__ Y, float* __restrict__ out) {
  const int t = blockIdx.x, k = threadIdx.x;
  if (k < DPn) {
    const float ph = fmaf(J[(size_t)t * DINn + DYn + k], scP[k], mnP[k]);
    out[O_P1 + t * DPn + k] = ph * Pp[t * DPn + k];
    out[O_PU + t * DPn + k] = fmaxf(ph - UppP[t * DPn + k], 0.f);
    out[O_PL + t * DPn + k] = fmaxf(LowP[t * DPn + k] - ph, 0.f);
  }
  if (k < DYn) {
    const float yh = fmaf(Y[(size_t)t * 96 + k], scY[k], mnY[k]);
    out[O_YU + t * DYn + k] = fmaxf(yh - UppY[t * DYn + k], 0.f);
    out[O_YL + t * DYn + k] = fmaxf(LowY[t * DYn + k] - yh, 0.f);
  }
}

extern "C" void kernel_launch(void* const* d_in, const int* in_sizes, int n_in,
                              void* d_out, int out_size, void* d_ws, size_t ws_size,
                              hipStream_t stream) {
  const float* J    = (const float*)d_in[0];
  const float* Pp   = (const float*)d_in[1];
  const float* UppY = (const float*)d_in[2];
  const float* LowY = (const float*)d_in[3];
  const float* UppP = (const float*)d_in[4];
  const float* LowP = (const float*)d_in[5];
  const float* W1   = (const float*)d_in[6];
  const float* b1   = (const float*)d_in[7];
  const float* W2   = (const float*)d_in[8];
  const float* b2   = (const float*)d_in[9];
  const float* W3   = (const float*)d_in[10];
  const float* b3   = (const float*)d_in[11];
  const float* W4   = (const float*)d_in[12];
  const float* b4   = (const float*)d_in[13];
  const float* scY  = (const float*)d_in[14];
  const float* mnY  = (const float*)d_in[15];
  const float* scP  = (const float*)d_in[16];
  const float* mnP  = (const float*)d_in[17];
  float* out = (float*)d_out;

  if (ws_size < WS_NEED) return;  // R4 measured ws >= 70.7 MB; loud failure otherwise

  char* base = (char*)d_ws;
  uint32* W2T = (uint32*)(base + O_W2T);
  uint32* W3T = (uint32*)(base + O_W3T);
  unsigned short* W1T = (unsigned short*)(base + O_W1T);
  float* UP  = (float*)(base + O_UP);
  float* h1x = (float*)(base + O_H1X);
  float* h2x = (float*)(base + O_H2X);
  float* P4  = (float*)(base + O_P4);
  float* Y   = (float*)(base + O_Y);
  unsigned* bar = (unsigned*)(base + O_BAR);

  zero_bar<<<dim3(5), dim3(256), 0, stream>>>(bar);
  t44_kernel<<<dim3(8192), dim3(256), 0, stream>>>(W2, W3, W2T, W3T);
  t1_kernel<<<dim3(64), dim3(256), 0, stream>>>(W1, W1T);
  up_kernel<<<dim3(TSn * 8), dim3(512), 0, stream>>>(J, W1, b1, UP);
  scan2_kernel<<<dim3(NB), dim3(BLK), 0, stream>>>(
      J, b2, b3, b4, W4, W1T, W2T, W3T, UP, h1x, h2x, P4, Y, bar);
  post_kernel<<<dim3(96), dim3(128), 0, stream>>>(
      J, Pp, UppY, LowY, UppP, LowP, scY, mnY, scP, mnP, Y, out);
}

// Round 6
// 3965.670 us; speedup vs baseline: 2.0780x; 1.0858x over previous
//
#include <hip/hip_runtime.h>

#define NB 256
#define BLK 1024
#define TSn 95
#define DYn 90
#define DPn 80
#define DINn 170
#define Hn 4096

typedef unsigned int uint32;

// ---- ws byte offsets ----
#define O_W2T 0ull             // 4096x4096 bf16 (col-major rows of 8KB)
#define O_W3T 33554432ull
#define O_W1T 67108864ull      // 4096 x 96 bf16
#define O_UP  67895296ull      // 95 x 4096 f32
#define O_H1X 69451776ull      // 2048 u32 (bf16x2)
#define O_H2X 69459968ull      // 2048 u32
#define O_P4  69468160ull      // 256 x 48 u32 (bf16x2 pairs, 45 used)
#define O_Y   69517312ull      // 96 x 96 f32
#define O_BAR 69554176ull      // 1088 u32
#define WS_NEED 69558528ull

// out float offsets
#define O_YU 0
#define O_YL 8640
#define O_P1 17280
#define O_PU 24960
#define O_PL 32640

__device__ __forceinline__ uint32 ld_cgu(const uint32* p) {
  return __hip_atomic_load(p, __ATOMIC_RELAXED, __HIP_MEMORY_SCOPE_AGENT);
}
__device__ __forceinline__ void st_cgu(uint32* p, uint32 v) {
  __hip_atomic_store(p, v, __ATOMIC_RELAXED, __HIP_MEMORY_SCOPE_AGENT);
}
__device__ __forceinline__ unsigned f2bf(float f) {
  uint32 u = __float_as_uint(f);
  return (u + 0x7fffu + ((u >> 16) & 1u)) >> 16;  // RNE
}
__device__ __forceinline__ float bflo(uint32 u) { return __uint_as_float(u << 16); }
__device__ __forceinline__ float bfhi(uint32 u) { return __uint_as_float(u & 0xffff0000u); }

__device__ __forceinline__ float wred(float v) {
#pragma unroll
  for (int o = 32; o > 0; o >>= 1) v += __shfl_xor(v, o, 64);
  return v;
}

// Direct-spin grid barrier: arrival on 64 distributed lines (cumulative),
// every block's wave 0 polls all 64 lines and sums. Relaxed agent scope only
// (no acquire/release -> no L2 invalidation). __syncthreads drains vmcnt(0)
// so prior st_cgu stores are globally issued before the arrival RMW.
__device__ void gbar(unsigned* bar, unsigned target, int bid, int tid) {
  __syncthreads();
  if (tid < 64) {
    if (tid == 0)
      __hip_atomic_fetch_add(&bar[(bid & 63) * 16], 1u, __ATOMIC_RELAXED, __HIP_MEMORY_SCOPE_AGENT);
    unsigned spins = 0;
    for (;;) {
      unsigned v = __hip_atomic_load(&bar[tid * 16], __ATOMIC_RELAXED, __HIP_MEMORY_SCOPE_AGENT);
#pragma unroll
      for (int o = 32; o > 0; o >>= 1) v += __shfl_xor(v, o, 64);
      if (v >= target) break;
      __builtin_amdgcn_s_sleep(1);
      if (++spins > (1u << 21)) break;  // escape hatch, never hit when healthy
    }
  }
  __syncthreads();
}

// ---------------- prologue kernels ----------------
extern "C" __global__ void zero_bar(unsigned* bar) {
  int i = blockIdx.x * 256 + threadIdx.x;
  if (i < 1088) bar[i] = 0u;
}

// Transpose 4096x4096 f32 -> bf16x2-packed rows. grid 8192 (2 matrices).
extern "C" __global__ __launch_bounds__(256)
void t44_kernel(const float* __restrict__ W2, const float* __restrict__ W3,
                uint32* __restrict__ W2T, uint32* __restrict__ W3T) {
  const int mat = blockIdx.x >> 12;
  const int m = blockIdx.x & 4095;
  const float* src = mat ? W3 : W2;
  uint32* dst = mat ? W3T : W2T;
  const int j0 = (m >> 6) * 64, k0 = (m & 63) * 64;
  const int t = threadIdx.x;
  __shared__ float lds[64][65];
  const int jl = t & 63, kb = t >> 6;
#pragma unroll
  for (int i = 0; i < 16; ++i) {
    const int kl = kb + 4 * i;
    lds[kl][jl] = src[(size_t)(k0 + kl) * Hn + j0 + jl];
  }
  __syncthreads();
  const int kp = t & 31, jb = t >> 5;
#pragma unroll
  for (int i = 0; i < 8; ++i) {
    const int jr = jb + 8 * i;
    uint32 v = f2bf(lds[2 * kp][jr]) | (f2bf(lds[2 * kp + 1][jr]) << 16);
    dst[(size_t)(j0 + jr) * 2048 + (k0 >> 1) + kp] = v;
  }
}

// W1 y-part (rows q<90) -> W1T[j][q] bf16, stride 96 (zero-pad q>=90).
extern "C" __global__ __launch_bounds__(256)
void t1_kernel(const float* __restrict__ W1, unsigned short* __restrict__ W1T) {
  const int j0 = blockIdx.x * 64;
  const int t = threadIdx.x;
  const int jl = t & 63, q0 = t >> 6;
  for (int q = q0; q < 96; q += 4) {
    float v = (q < DYn) ? W1[(size_t)q * Hn + j0 + jl] : 0.f;
    W1T[(size_t)(j0 + jl) * 96 + q] = (unsigned short)f2bf(v);
  }
}

extern "C" __global__ __launch_bounds__(512)
void up_kernel(const float* __restrict__ J, const float* __restrict__ W1,
               const float* __restrict__ b1, float* __restrict__ UP) {
  const int t = blockIdx.x >> 3, jc = blockIdx.x & 7;
  const int j = jc * 512 + threadIdx.x;
  __shared__ float us[DPn];
  if (threadIdx.x < DPn) us[threadIdx.x] = J[(size_t)t * DINn + DYn + threadIdx.x];
  __syncthreads();
  float acc = b1[j];
#pragma unroll 8
  for (int k = 0; k < DPn; ++k) acc = fmaf(us[k], W1[(size_t)(DYn + k) * Hn + j], acc);
  UP[(size_t)t * Hn + j] = acc;
}

// ---------------- scan ----------------
// Dot of a register-prefetched bf16x2 weight row against the packed h-vector
// in LDS. pf[i] = row uint4 (i*64 + l); covers k = i*512 + l*8 .. +7.
__device__ __forceinline__ float dot_pf(const uint4* pf, const uint32* hvp, int l) {
  float a = 0.f;
#pragma unroll
  for (int i = 0; i < 8; ++i) {
    const uint4 hu = *(const uint4*)&hvp[i * 256 + l * 4];
    const uint4 u = pf[i];
    a = fmaf(bflo(hu.x), bflo(u.x), a); a = fmaf(bfhi(hu.x), bfhi(u.x), a);
    a = fmaf(bflo(hu.y), bflo(u.y), a); a = fmaf(bfhi(hu.y), bfhi(u.y), a);
    a = fmaf(bflo(hu.z), bflo(u.z), a); a = fmaf(bfhi(hu.z), bfhi(u.z), a);
    a = fmaf(bflo(hu.w), bflo(u.w), a); a = fmaf(bfhi(hu.w), bfhi(u.w), a);
  }
  return wred(a);
}

extern "C" __global__ __launch_bounds__(BLK, 1)
void scan3_kernel(const float* __restrict__ J, const float* __restrict__ b2,
                  const float* __restrict__ b3, const float* __restrict__ b4,
                  const float* __restrict__ W4, const unsigned short* __restrict__ W1T,
                  const uint32* __restrict__ W2T, const uint32* __restrict__ W3T,
                  const float* __restrict__ UP, uint32* __restrict__ h1xp,
                  uint32* __restrict__ h2xp, uint32* __restrict__ P4p,
                  float* __restrict__ Y, unsigned* __restrict__ bar) {
  const int bid = blockIdx.x, tid = threadIdx.x;
  const int w = tid >> 6, l = tid & 63;
  const int j0 = bid * 16;
  const int j = j0 + w;  // this wave's output column in big layers

  __shared__ uint32 hvp[2048];
  __shared__ float ys[96];
  __shared__ float2 ysp2[16][48];
  __shared__ float h1s[16];
  __shared__ float h3L[16];
  __shared__ float y4L[96];

  unsigned tgt = 0;
  uint4 pf[8];

  // prefetch W2 row for t=0
  {
    const uint4* wrow = (const uint4*)W2T + (size_t)j * 512 + l;
#pragma unroll
    for (int i = 0; i < 8; ++i) pf[i] = wrow[i * 64];
  }

  for (int t = 0; t < TSn; ++t) {
    // ---- phase A: materialize y_t (redundant per block) ----
    if (t == 0) {
      if (tid < DYn) ys[tid] = J[tid];
    } else {
      // y-reduce over 256 bf16x2-packed partials (written before last barrier)
      if (l < 45) {
        const uint32* pr = P4p + l + (size_t)w * 48;
        float sx = 0.f, sy = 0.f;
#pragma unroll
        for (int k = 0; k < 16; ++k) {
          uint32 v = ld_cgu(pr + (size_t)k * 16 * 48);
          sx += bflo(v); sy += bfhi(v);
        }
        ysp2[w][l] = make_float2(sx, sy);
      }
      __syncthreads();
      if (tid < 45) {
        float sx = 0.f, sy = 0.f;
#pragma unroll
        for (int r = 0; r < 16; ++r) { float2 p = ysp2[r][tid]; sx += p.x; sy += p.y; }
        ys[2 * tid] = b4[2 * tid] + sx;
        ys[2 * tid + 1] = b4[2 * tid + 1] + sy;
      }
    }
    __syncthreads();
    if (bid == 0 && tid < DYn) Y[(size_t)t * 96 + tid] = ys[tid];

    // ---- h1 slice: wave w -> column j ----
    {
      const unsigned short* wr = W1T + (size_t)j * 96;
      float a = 0.f;
      if (l < DYn) a = ys[l] * bflo((uint32)wr[l]);
      if (l < DYn - 64) a = fmaf(ys[64 + l], bflo((uint32)wr[64 + l]), a);
      a = wred(a);
      if (l == 0) h1s[w] = fmaxf(UP[(size_t)t * Hn + j] + a, 0.f);
    }
    __syncthreads();
    if (tid < 8)
      st_cgu(&h1xp[bid * 8 + tid], f2bf(h1s[2 * tid]) | (f2bf(h1s[2 * tid + 1]) << 16));
    tgt += NB; gbar(bar, tgt, bid, tid);

    // ---- phase B: h2 = relu(b2 + W2T . h1) ----
    hvp[tid] = ld_cgu(&h1xp[tid]);
    hvp[tid + 1024] = ld_cgu(&h1xp[tid + 1024]);
    __syncthreads();
    {
      float a = dot_pf(pf, hvp, l);
      if (l == 0) h1s[w] = fmaxf(b2[j] + a, 0.f);
    }
    // prefetch W3 row (overlaps h2 publish + barrier)
    {
      const uint4* wrow = (const uint4*)W3T + (size_t)j * 512 + l;
#pragma unroll
      for (int i = 0; i < 8; ++i) pf[i] = wrow[i * 64];
    }
    __syncthreads();
    if (tid < 8)
      st_cgu(&h2xp[bid * 8 + tid], f2bf(h1s[2 * tid]) | (f2bf(h1s[2 * tid + 1]) << 16));
    tgt += NB; gbar(bar, tgt, bid, tid);

    // ---- phase C: h3 slice (local) + W4 partial -> P4 ----
    hvp[tid] = ld_cgu(&h2xp[tid]);
    hvp[tid + 1024] = ld_cgu(&h2xp[tid + 1024]);
    __syncthreads();
    {
      float a = dot_pf(pf, hvp, l);
      if (l == 0) h3L[w] = fmaxf(b3[j] + a, 0.f);
    }
    __syncthreads();
    if (tid < DYn) {
      float acc = 0.f;
#pragma unroll
      for (int jj = 0; jj < 16; ++jj)
        acc = fmaf(h3L[jj], W4[(size_t)(j0 + jj) * DYn + tid], acc);
      y4L[tid] = acc;
    }
    __syncthreads();
    if (tid < 45)
      st_cgu(&P4p[bid * 48 + tid], f2bf(y4L[2 * tid]) | (f2bf(y4L[2 * tid + 1]) << 16));
    // prefetch W2 row for step t+1 (overlaps P4 publish + barrier + y-reduce)
    {
      const uint4* wrow = (const uint4*)W2T + (size_t)j * 512 + l;
#pragma unroll
      for (int i = 0; i < 8; ++i) pf[i] = wrow[i * 64];
    }
    tgt += NB; gbar(bar, tgt, bid, tid);
  }

  // ---- final y (t = 95), block 0 only ----
  if (bid == 0) {
    if (l < 45) {
      const uint32* pr = P4p + l + (size_t)w * 48;
      float sx = 0.f, sy = 0.f;
#pragma unroll
      for (int k = 0; k < 16; ++k) {
        uint32 v = ld_cgu(pr + (size_t)k * 16 * 48);
        sx += bflo(v); sy += bfhi(v);
      }
      ysp2[w][l] = make_float2(sx, sy);
    }
    __syncthreads();
    if (tid < 45) {
      float sx = 0.f, sy = 0.f;
#pragma unroll
      for (int r = 0; r < 16; ++r) { float2 p = ysp2[r][tid]; sx += p.x; sy += p.y; }
      Y[(size_t)TSn * 96 + 2 * tid] = b4[2 * tid] + sx;
      Y[(size_t)TSn * 96 + 2 * tid + 1] = b4[2 * tid + 1] + sy;
    }
  }
}

// ---------------- epilogue ----------------
extern "C" __global__ void post_kernel(const float* __restrict__ J, const float* __restrict__ Pp,
                                       const float* __restrict__ UppY, const float* __restrict__ LowY,
                                       const float* __restrict__ UppP, const float* __restrict__ LowP,
                                       const float* __restrict__ scY, const float* __restrict__ mnY,
                                       const float* __restrict__ scP, const float* __restrict__ mnP,
                                       const float* __restrict__ Y, float* __restrict__ out) {
  const int t = blockIdx.x, k = threadIdx.x;
  if (k < DPn) {
    const float ph = fmaf(J[(size_t)t * DINn + DYn + k], scP[k], mnP[k]);
    out[O_P1 + t * DPn + k] = ph * Pp[t * DPn + k];
    out[O_PU + t * DPn + k] = fmaxf(ph - UppP[t * DPn + k], 0.f);
    out[O_PL + t * DPn + k] = fmaxf(LowP[t * DPn + k] - ph, 0.f);
  }
  if (k < DYn) {
    const float yh = fmaf(Y[(size_t)t * 96 + k], scY[k], mnY[k]);
    out[O_YU + t * DYn + k] = fmaxf(yh - UppY[t * DYn + k], 0.f);
    out[O_YL + t * DYn + k] = fmaxf(LowY[t * DYn + k] - yh, 0.f);
  }
}

extern "C" void kernel_launch(void* const* d_in, const int* in_sizes, int n_in,
                              void* d_out, int out_size, void* d_ws, size_t ws_size,
                              hipStream_t stream) {
  const float* J    = (const float*)d_in[0];
  const float* Pp   = (const float*)d_in[1];
  const float* UppY = (const float*)d_in[2];
  const float* LowY = (const float*)d_in[3];
  const float* UppP = (const float*)d_in[4];
  const float* LowP = (const float*)d_in[5];
  const float* W1   = (const float*)d_in[6];
  const float* b1   = (const float*)d_in[7];
  const float* W2   = (const float*)d_in[8];
  const float* b2   = (const float*)d_in[9];
  const float* W3   = (const float*)d_in[10];
  const float* b3   = (const float*)d_in[11];
  const float* W4   = (const float*)d_in[12];
  const float* b4   = (const float*)d_in[13];
  const float* scY  = (const float*)d_in[14];
  const float* mnY  = (const float*)d_in[15];
  const float* scP  = (const float*)d_in[16];
  const float* mnP  = (const float*)d_in[17];
  float* out = (float*)d_out;

  if (ws_size < WS_NEED) return;  // R5 confirmed ws >= 69.7 MB

  char* base = (char*)d_ws;
  uint32* W2T = (uint32*)(base + O_W2T);
  uint32* W3T = (uint32*)(base + O_W3T);
  unsigned short* W1T = (unsigned short*)(base + O_W1T);
  float* UP   = (float*)(base + O_UP);
  uint32* h1xp = (uint32*)(base + O_H1X);
  uint32* h2xp = (uint32*)(base + O_H2X);
  uint32* P4p  = (uint32*)(base + O_P4);
  float* Y    = (float*)(base + O_Y);
  unsigned* bar = (unsigned*)(base + O_BAR);

  zero_bar<<<dim3(5), dim3(256), 0, stream>>>(bar);
  t44_kernel<<<dim3(8192), dim3(256), 0, stream>>>(W2, W3, W2T, W3T);
  t1_kernel<<<dim3(64), dim3(256), 0, stream>>>(W1, W1T);
  up_kernel<<<dim3(TSn * 8), dim3(512), 0, stream>>>(J, W1, b1, UP);
  scan3_kernel<<<dim3(NB), dim3(BLK), 0, stream>>>(
      J, b2, b3, b4, W4, W1T, W2T, W3T, UP, h1xp, h2xp, P4p, Y, bar);
  post_kernel<<<dim3(96), dim3(128), 0, stream>>>(
      J, Pp, UppY, LowY, UppP, LowP, scY, mnY, scP, mnP, Y, out);
}